// Round 1
// baseline (75.325 us; speedup 1.0000x reference)
//
#include <hip/hip_runtime.h>
#include <hip/hip_bf16.h>
#include <math.h>

// HOG forward: im (16,3,512,512) f32 -> (16,1,31,31,2,2,9) f32
// CELL=16, BLOCK=2, NBINS=9; Hc=Wc=32, Hb=Wb=31, P=256

#define IMG_H 512
#define IMG_W 512
#define NCH 3
#define NB_ 16
#define HC 32
#define WC 32
#define HB 31
#define WB 31
#define NBINS 9

__device__ __forceinline__ int refl(int i, int n) {
    if (i < 0) i = -i;
    else if (i >= n) i = 2 * n - 2 - i;
    return i;
}

// One block (256 threads) per cell: stage 18x18x3 halo in LDS, per-pixel
// Sobel + channel argmax + atan2 + soft binning, LDS-atomic 9-bin histogram.
__global__ __launch_bounds__(256) void hog_hist_kernel(const float* __restrict__ im,
                                                       float* __restrict__ hist) {
    const int cell = blockIdx.x;              // b*1024 + cy*32 + cx
    const int b  = cell >> 10;
    const int cy = (cell >> 5) & 31;
    const int cx = cell & 31;

    __shared__ float s[NCH][18][18];
    __shared__ float h[NBINS];

    const int t = threadIdx.x;
    if (t < NBINS) h[t] = 0.0f;

    const int y0 = cy * 16 - 1;
    const int x0 = cx * 16 - 1;
    const float* imb = im + (size_t)b * NCH * IMG_H * IMG_W;

    // stage 3 * 18*18 = 972 elements
    for (int i = t; i < NCH * 18 * 18; i += 256) {
        int c = i / 324;
        int r = i - c * 324;
        int yy = r / 18;
        int xx = r - yy * 18;
        int gy_ = refl(y0 + yy, IMG_H);
        int gx_ = refl(x0 + xx, IMG_W);
        s[c][yy][xx] = imb[((size_t)c * IMG_H + gy_) * IMG_W + gx_];
    }
    __syncthreads();

    const int ty = t >> 4;
    const int tx = t & 15;

    // Sobel per channel; pick channel with max magnitude (first-max tie-break)
    float bn = -1.0f, bgx = 0.0f, bgy = 0.0f;
#pragma unroll
    for (int c = 0; c < NCH; ++c) {
        float a00 = s[c][ty][tx],     a01 = s[c][ty][tx + 1],     a02 = s[c][ty][tx + 2];
        float a10 = s[c][ty + 1][tx],                             a12 = s[c][ty + 1][tx + 2];
        float a20 = s[c][ty + 2][tx], a21 = s[c][ty + 2][tx + 1], a22 = s[c][ty + 2][tx + 2];
        float gx = (a02 - a00) + 2.0f * (a12 - a10) + (a22 - a20);
        float gy = (a20 - a00) + 2.0f * (a21 - a01) + (a22 - a02);
        float n = sqrtf(gx * gx + gy * gy);
        if (n > bn) { bn = n; bgx = gx; bgy = gy; }
    }

    const float PI_F  = (float)M_PI;           // 3.14159274f
    const float GAIN  = (float)(9.0 / M_PI);   // nb/pi
    const float BINW  = (float)(M_PI / 9.0);   // pi/9

    // phase = mod(atan2(gy,gx), pi)  -- jnp.mod semantics (sign of divisor)
    float p = atan2f(bgy, bgx);
    p = fmodf(p, PI_F);
    if (p < 0.0f) p += PI_F;

    float fp = GAIN * p;
    int left = (int)floorf(fp);                // 0..9 (9 only when p==pi)
    float prct = GAIN * (p - (float)left * BINW);
    int li = left % NBINS;
    int ri = (left + 1) % NBINS;

    atomicAdd(&h[li], (1.0f - prct) * bn);
    atomicAdd(&h[ri], prct * bn);
    __syncthreads();

    if (t < NBINS) hist[(size_t)cell * NBINS + t] = h[t] * (1.0f / 256.0f);
}

// One thread per output block: gather 2x2 cells x 9 bins, L2-Hys normalize.
__global__ __launch_bounds__(256) void hog_norm_kernel(const float* __restrict__ hist,
                                                       float* __restrict__ out) {
    int idx = blockIdx.x * 256 + threadIdx.x;  // b*961 + i*31 + j
    if (idx >= NB_ * HB * WB) return;
    int b = idx / (HB * WB);
    int r = idx - b * (HB * WB);
    int i = r / WB;
    int j = r - i * WB;

    float v[36];
    float ss = 0.0f;
#pragma unroll
    for (int bi = 0; bi < 2; ++bi) {
#pragma unroll
        for (int bj = 0; bj < 2; ++bj) {
            const float* hp = hist + (size_t)(((b * HC) + (i + bi)) * WC + (j + bj)) * NBINS;
#pragma unroll
            for (int k = 0; k < NBINS; ++k) {
                float x = hp[k];
                v[(bi * 2 + bj) * NBINS + k] = x;
                ss += x * x;
            }
        }
    }
    float inv1 = 1.0f / (sqrtf(ss) + 1e-10f);
    float ss2 = 0.0f;
#pragma unroll
    for (int k = 0; k < 36; ++k) {
        float tt = fminf(v[k] * inv1, 0.2f);
        v[k] = tt;
        ss2 += tt * tt;
    }
    float inv2 = 1.0f / (sqrtf(ss2) + 1e-10f);
    float* op = out + (size_t)idx * 36;
#pragma unroll
    for (int k = 0; k < 36; ++k) op[k] = v[k] * inv2;
}

extern "C" void kernel_launch(void* const* d_in, const int* in_sizes, int n_in,
                              void* d_out, int out_size, void* d_ws, size_t ws_size,
                              hipStream_t stream) {
    const float* im = (const float*)d_in[0];
    float* out = (float*)d_out;
    float* hist = (float*)d_ws;  // 16*32*32*9 floats = 589,824 bytes

    hog_hist_kernel<<<NB_ * HC * WC, 256, 0, stream>>>(im, hist);

    int nout_blocks = NB_ * HB * WB;           // 15376
    hog_norm_kernel<<<(nout_blocks + 255) / 256, 256, 0, stream>>>(hist, out);
}

// Round 2
// 68.160 us; speedup vs baseline: 1.1051x; 1.1051x over previous
//
#include <hip/hip_runtime.h>
#include <hip/hip_bf16.h>
#include <math.h>

// HOG forward: im (16,3,512,512) f32 -> (16,1,31,31,2,2,9) f32
// CELL=16, BLOCK=2, NBINS=9; Hc=Wc=32, Hb=Wb=31, P=256

#define IMG_H 512
#define IMG_W 512
#define NCH 3
#define NB_ 16
#define HC 32
#define WC 32
#define HB 31
#define WB 31
#define NBINS 9

__device__ __forceinline__ int refl(int i, int n) {
    if (i < 0) i = -i;
    else if (i >= n) i = 2 * n - 2 - i;
    return i;
}

// Tile: 64x16 pixels (4 cells in x, 1 in y) per 256-thread block.
// LDS: [3 ch][18 rows][72] (x: 3 = left halo, 4..67 = interior, 68 = right halo)
__global__ __launch_bounds__(256) void hog_hist_kernel(const float* __restrict__ im,
                                                       float* __restrict__ hist) {
    const int bid = blockIdx.x;             // b*256 + cy*8 + cxg
    const int b   = bid >> 8;
    const int cy  = (bid >> 3) & 31;
    const int cxg = bid & 7;                // group of 4 cells in x

    __shared__ __align__(16) float sT[NCH][18][72];
    __shared__ float sh[4][NBINS];

    const int t = threadIdx.x;
    if (t < 4 * NBINS) sh[t / NBINS][t % NBINS] = 0.0f;

    const int y0 = cy * 16 - 1;             // global row of LDS row 0
    const int x0 = cxg * 64;                // global col of LDS col 4
    const float* imb = im + (size_t)b * NCH * IMG_H * IMG_W;

    // ---- stage interior: 54 rows (3ch x 18) x 64 floats, as float4 ----
    {
        const int x4 = t & 15;              // float4 index within row
        const int r0 = t >> 4;              // row id base (0..15)
#pragma unroll
        for (int k = 0; k < 4; ++k) {
            int rowid = r0 + 16 * k;        // 0..63
            if (rowid < NCH * 18) {
                int c  = rowid / 18;
                int yy = rowid - c * 18;
                int gy = refl(y0 + yy, IMG_H);
                const float4 v = *(const float4*)(imb + ((size_t)c * IMG_H + gy) * IMG_W + x0 + 4 * x4);
                *(float4*)&sT[c][yy][4 + 4 * x4] = v;
            }
        }
        // halo columns: 3ch x 18 rows x 2 sides = 108 scalars
        if (t < 108) {
            int side = t & 1;
            int rid  = t >> 1;
            int c    = rid / 18;
            int yy   = rid - c * 18;
            int gy   = refl(y0 + yy, IMG_H);
            int gx   = refl(side ? x0 + 64 : x0 - 1, IMG_W);
            sT[c][yy][side ? 68 : 3] = imb[((size_t)c * IMG_H + gy) * IMG_W + gx];
        }
    }
    __syncthreads();

    // ---- compute: each thread owns pixel column px, rows r0..r0+3 ----
    const int px = t & 63;
    const int pr = (t >> 6) * 4;            // first pixel row (0,4,8,12)
    const int lx = 4 + px;                  // LDS x of pixel center

    float bn[4]  = {-1.0f, -1.0f, -1.0f, -1.0f};
    float bgx[4] = {0, 0, 0, 0};
    float bgy[4] = {0, 0, 0, 0};

#pragma unroll
    for (int c = 0; c < NCH; ++c) {
        float a[6][3];
#pragma unroll
        for (int j = 0; j < 6; ++j) {
            a[j][0] = sT[c][pr + j][lx - 1];
            a[j][1] = sT[c][pr + j][lx];
            a[j][2] = sT[c][pr + j][lx + 1];
        }
#pragma unroll
        for (int p = 0; p < 4; ++p) {
            // identical association to the verified round-1 kernel:
            float gx = (a[p][2] - a[p][0]) + 2.0f * (a[p + 1][2] - a[p + 1][0]) + (a[p + 2][2] - a[p + 2][0]);
            float gy = (a[p + 2][0] - a[p][0]) + 2.0f * (a[p + 2][1] - a[p][1]) + (a[p + 2][2] - a[p][2]);
            float n = sqrtf(gx * gx + gy * gy);
            if (n > bn[p]) { bn[p] = n; bgx[p] = gx; bgy[p] = gy; }
        }
    }

    const float PI_F  = (float)M_PI;
    const float HPI_F = (float)(M_PI / 2.0);
    const float GAIN  = (float)(9.0 / M_PI);
    const float BINW  = (float)(M_PI / 9.0);
    // minimax odd poly for atan on [0,1], max err ~2e-5 rad
    const float C1  = 0.99997726f, C3 = -0.33262347f, C5 = 0.19354346f;
    const float C7  = -0.11643287f, C9 = 0.05265332f, C11 = -0.01172120f;

    const int cl = px >> 4;                 // local cell 0..3

#pragma unroll
    for (int p = 0; p < 4; ++p) {
        float gx = bgx[p], gy = bgy[p], n = bn[p];
        float ax = fabsf(gx), ay = fabsf(gy);
        float mn = fminf(ax, ay), mx = fmaxf(ax, ay);
        float r  = __fdividef(mn, mx + 1e-37f);
        float r2 = r * r;
        float at = r * (C1 + r2 * (C3 + r2 * (C5 + r2 * (C7 + r2 * (C9 + r2 * C11)))));
        if (ay > ax) at = HPI_F - at;
        if ((__float_as_uint(gx) ^ __float_as_uint(gy)) & 0x80000000u) at = PI_F - at;
        // at = atan2(gy,gx) mod pi, in [0, pi]

        float fp_ = GAIN * at;
        int left  = (int)floorf(fp_);       // 0..9
        float prct = GAIN * (at - (float)left * BINW);
        int li = (left >= NBINS) ? left - NBINS : left;
        int ri = (li == NBINS - 1) ? 0 : li + 1;

        atomicAdd(&sh[cl][li], (1.0f - prct) * n);
        atomicAdd(&sh[cl][ri], prct * n);
    }
    __syncthreads();

    if (t < 4 * NBINS) {
        int c_local = t / NBINS;
        int bin     = t - c_local * NBINS;
        int cellX   = cxg * 4 + c_local;
        size_t cell = ((size_t)b * HC + cy) * WC + cellX;
        hist[cell * NBINS + bin] = sh[c_local][bin] * (1.0f / 256.0f);
    }
}

// One thread per output block: gather 2x2 cells x 9 bins, L2-Hys normalize.
__global__ __launch_bounds__(256) void hog_norm_kernel(const float* __restrict__ hist,
                                                       float* __restrict__ out) {
    int idx = blockIdx.x * 256 + threadIdx.x;  // b*961 + i*31 + j
    if (idx >= NB_ * HB * WB) return;
    int b = idx / (HB * WB);
    int r = idx - b * (HB * WB);
    int i = r / WB;
    int j = r - i * WB;

    float v[36];
    float ss = 0.0f;
#pragma unroll
    for (int bi = 0; bi < 2; ++bi) {
#pragma unroll
        for (int bj = 0; bj < 2; ++bj) {
            const float* hp = hist + (size_t)(((b * HC) + (i + bi)) * WC + (j + bj)) * NBINS;
#pragma unroll
            for (int k = 0; k < NBINS; ++k) {
                float x = hp[k];
                v[(bi * 2 + bj) * NBINS + k] = x;
                ss += x * x;
            }
        }
    }
    float inv1 = 1.0f / (sqrtf(ss) + 1e-10f);
    float ss2 = 0.0f;
#pragma unroll
    for (int k = 0; k < 36; ++k) {
        float tt = fminf(v[k] * inv1, 0.2f);
        v[k] = tt;
        ss2 += tt * tt;
    }
    float inv2 = 1.0f / (sqrtf(ss2) + 1e-10f);
    float* op = out + (size_t)idx * 36;
#pragma unroll
    for (int k = 0; k < 36; ++k) op[k] = v[k] * inv2;
}

extern "C" void kernel_launch(void* const* d_in, const int* in_sizes, int n_in,
                              void* d_out, int out_size, void* d_ws, size_t ws_size,
                              hipStream_t stream) {
    const float* im = (const float*)d_in[0];
    float* out = (float*)d_out;
    float* hist = (float*)d_ws;  // 16*32*32*9 floats = 589,824 bytes

    hog_hist_kernel<<<NB_ * HC * 8, 256, 0, stream>>>(im, hist);

    int nout_blocks = NB_ * HB * WB;           // 15376
    hog_norm_kernel<<<(nout_blocks + 255) / 256, 256, 0, stream>>>(hist, out);
}

// Round 3
// 36.886 us; speedup vs baseline: 2.0421x; 1.8479x over previous
//
#include <hip/hip_runtime.h>
#include <hip/hip_bf16.h>
#include <math.h>

// HOG forward: im (16,3,512,512) f32 -> (16,1,31,31,2,2,9) f32
// CELL=16, BLOCK=2, NBINS=9; Hc=Wc=32, Hb=Wb=31, P=256

#define IMG_H 512
#define IMG_W 512
#define NCH 3
#define NB_ 16
#define HC 32
#define WC 32
#define HB 31
#define WB 31
#define NBINS 9

__device__ __forceinline__ int refl(int i, int n) {
    if (i < 0) i = -i;
    else if (i >= n) i = 2 * n - 2 - i;
    return i;
}

// Tile: 64x16 pixels (4 cells in x, 1 in y) per 256-thread block.
// LDS: [3 ch][18 rows][72] (x: 3 = left halo, 4..67 = interior, 68 = right halo)
// Histogram: per-thread register bins (one-hot cndmask) -> shfl_xor 16-lane
// reduce -> 4-wave LDS combine. NO atomics.
__global__ __launch_bounds__(256) void hog_hist_kernel(const float* __restrict__ im,
                                                       float* __restrict__ hist) {
    const int bid = blockIdx.x;             // b*256 + cy*8 + cxg
    const int b   = bid >> 8;
    const int cy  = (bid >> 3) & 31;
    const int cxg = bid & 7;                // group of 4 cells in x

    __shared__ __align__(16) float sT[NCH][18][72];
    __shared__ float swp[4][4][NBINS];      // [wave][local cell][bin]

    const int t = threadIdx.x;

    const int y0 = cy * 16 - 1;             // global row of LDS row 0
    const int x0 = cxg * 64;                // global col of LDS col 4
    const float* imb = im + (size_t)b * NCH * IMG_H * IMG_W;

    // ---- stage interior: 54 rows (3ch x 18) x 64 floats, as float4 ----
    {
        const int x4 = t & 15;              // float4 index within row
        const int r0 = t >> 4;              // row id base (0..15)
#pragma unroll
        for (int k = 0; k < 4; ++k) {
            int rowid = r0 + 16 * k;        // 0..63
            if (rowid < NCH * 18) {
                int c  = rowid / 18;
                int yy = rowid - c * 18;
                int gy = refl(y0 + yy, IMG_H);
                const float4 v = *(const float4*)(imb + ((size_t)c * IMG_H + gy) * IMG_W + x0 + 4 * x4);
                *(float4*)&sT[c][yy][4 + 4 * x4] = v;
            }
        }
        // halo columns: 3ch x 18 rows x 2 sides = 108 scalars
        if (t < 108) {
            int side = t & 1;
            int rid  = t >> 1;
            int c    = rid / 18;
            int yy   = rid - c * 18;
            int gy   = refl(y0 + yy, IMG_H);
            int gx   = refl(side ? x0 + 64 : x0 - 1, IMG_W);
            sT[c][yy][side ? 68 : 3] = imb[((size_t)c * IMG_H + gy) * IMG_W + gx];
        }
    }
    __syncthreads();

    // ---- compute: each thread owns pixel column px, rows pr..pr+3 ----
    const int px = t & 63;
    const int pr = (t >> 6) * 4;            // first pixel row (0,4,8,12)
    const int lx = 4 + px;                  // LDS x of pixel center

    float bn[4]  = {-1.0f, -1.0f, -1.0f, -1.0f};
    float bgx[4] = {0, 0, 0, 0};
    float bgy[4] = {0, 0, 0, 0};

#pragma unroll
    for (int c = 0; c < NCH; ++c) {
        float a[6][3];
#pragma unroll
        for (int j = 0; j < 6; ++j) {
            a[j][0] = sT[c][pr + j][lx - 1];
            a[j][1] = sT[c][pr + j][lx];
            a[j][2] = sT[c][pr + j][lx + 1];
        }
#pragma unroll
        for (int p = 0; p < 4; ++p) {
            // identical association to the verified round-1 kernel:
            float gx = (a[p][2] - a[p][0]) + 2.0f * (a[p + 1][2] - a[p + 1][0]) + (a[p + 2][2] - a[p + 2][0]);
            float gy = (a[p + 2][0] - a[p][0]) + 2.0f * (a[p + 2][1] - a[p][1]) + (a[p + 2][2] - a[p][2]);
            float n = sqrtf(gx * gx + gy * gy);
            if (n > bn[p]) { bn[p] = n; bgx[p] = gx; bgy[p] = gy; }
        }
    }

    const float PI_F  = (float)M_PI;
    const float HPI_F = (float)(M_PI / 2.0);
    const float GAIN  = (float)(9.0 / M_PI);
    const float BINW  = (float)(M_PI / 9.0);
    // minimax odd poly for atan on [0,1], max err ~2e-5 rad
    const float C1  = 0.99997726f, C3 = -0.33262347f, C5 = 0.19354346f;
    const float C7  = -0.11643287f, C9 = 0.05265332f, C11 = -0.01172120f;

    float acc[NBINS];
#pragma unroll
    for (int k = 0; k < NBINS; ++k) acc[k] = 0.0f;

#pragma unroll
    for (int p = 0; p < 4; ++p) {
        float gx = bgx[p], gy = bgy[p], n = bn[p];
        float ax = fabsf(gx), ay = fabsf(gy);
        float mn = fminf(ax, ay), mx = fmaxf(ax, ay);
        float r  = __fdividef(mn, mx + 1e-37f);
        float r2 = r * r;
        float at = r * (C1 + r2 * (C3 + r2 * (C5 + r2 * (C7 + r2 * (C9 + r2 * C11)))));
        if (ay > ax) at = HPI_F - at;
        if ((__float_as_uint(gx) ^ __float_as_uint(gy)) & 0x80000000u) at = PI_F - at;
        // at = atan2(gy,gx) mod pi, in [0, pi]

        float fp_ = GAIN * at;
        int left  = (int)floorf(fp_);       // 0..9
        float prct = GAIN * (at - (float)left * BINW);
        int li = (left >= NBINS) ? left - NBINS : left;
        int ri = (li == NBINS - 1) ? 0 : li + 1;

        float w_l = (1.0f - prct) * n;
        float w_r = prct * n;
        // branchless one-hot accumulate into register bins (static indices)
#pragma unroll
        for (int k = 0; k < NBINS; ++k) {
            acc[k] += (li == k) ? w_l : 0.0f;
            acc[k] += (ri == k) ? w_r : 0.0f;
        }
    }

    // ---- reduce: 16-lane butterfly within each cell group ----
#pragma unroll
    for (int m = 1; m <= 8; m <<= 1) {
#pragma unroll
        for (int k = 0; k < NBINS; ++k)
            acc[k] += __shfl_xor(acc[k], m, 64);
    }

    const int lane = t & 63;
    const int wv   = t >> 6;
    if ((lane & 15) == 0) {
        const int cl = lane >> 4;
#pragma unroll
        for (int k = 0; k < NBINS; ++k) swp[wv][cl][k] = acc[k];
    }
    __syncthreads();

    if (t < 4 * NBINS) {
        int c_local = t / NBINS;
        int bin     = t - c_local * NBINS;
        float sum = swp[0][c_local][bin] + swp[1][c_local][bin]
                  + swp[2][c_local][bin] + swp[3][c_local][bin];
        int cellX   = cxg * 4 + c_local;
        size_t cell = ((size_t)b * HC + cy) * WC + cellX;
        hist[cell * NBINS + bin] = sum * (1.0f / 256.0f);
    }
}

// One thread per output block: gather 2x2 cells x 9 bins, L2-Hys normalize.
__global__ __launch_bounds__(256) void hog_norm_kernel(const float* __restrict__ hist,
                                                       float* __restrict__ out) {
    int idx = blockIdx.x * 256 + threadIdx.x;  // b*961 + i*31 + j
    if (idx >= NB_ * HB * WB) return;
    int b = idx / (HB * WB);
    int r = idx - b * (HB * WB);
    int i = r / WB;
    int j = r - i * WB;

    float v[36];
    float ss = 0.0f;
#pragma unroll
    for (int bi = 0; bi < 2; ++bi) {
#pragma unroll
        for (int bj = 0; bj < 2; ++bj) {
            const float* hp = hist + (size_t)(((b * HC) + (i + bi)) * WC + (j + bj)) * NBINS;
#pragma unroll
            for (int k = 0; k < NBINS; ++k) {
                float x = hp[k];
                v[(bi * 2 + bj) * NBINS + k] = x;
                ss += x * x;
            }
        }
    }
    float inv1 = 1.0f / (sqrtf(ss) + 1e-10f);
    float ss2 = 0.0f;
#pragma unroll
    for (int k = 0; k < 36; ++k) {
        float tt = fminf(v[k] * inv1, 0.2f);
        v[k] = tt;
        ss2 += tt * tt;
    }
    float inv2 = 1.0f / (sqrtf(ss2) + 1e-10f);
    float* op = out + (size_t)idx * 36;
#pragma unroll
    for (int k = 0; k < 36; ++k) op[k] = v[k] * inv2;
}

extern "C" void kernel_launch(void* const* d_in, const int* in_sizes, int n_in,
                              void* d_out, int out_size, void* d_ws, size_t ws_size,
                              hipStream_t stream) {
    const float* im = (const float*)d_in[0];
    float* out = (float*)d_out;
    float* hist = (float*)d_ws;  // 16*32*32*9 floats = 589,824 bytes

    hog_hist_kernel<<<NB_ * HC * 8, 256, 0, stream>>>(im, hist);

    int nout_blocks = NB_ * HB * WB;           // 15376
    hog_norm_kernel<<<(nout_blocks + 255) / 256, 256, 0, stream>>>(hist, out);
}

// Round 4
// 35.223 us; speedup vs baseline: 2.1385x; 1.0472x over previous
//
#include <hip/hip_runtime.h>
#include <hip/hip_bf16.h>
#include <math.h>

// HOG forward: im (16,3,512,512) f32 -> (16,1,31,31,2,2,9) f32
// CELL=16, BLOCK=2, NBINS=9; Hc=Wc=32, Hb=Wb=31, P=256

#define IMG_H 512
#define IMG_W 512
#define NCH 3
#define NB_ 16
#define HC 32
#define WC 32
#define HB 31
#define WB 31
#define NBINS 9

__device__ __forceinline__ int refl(int i, int n) {
    if (i < 0) i = -i;
    else if (i >= n) i = 2 * n - 2 - i;
    return i;
}

// Tile: 128x16 pixels (8 cells) per 256-thread block; 8 px/thread (2 cols x 4 rows).
// LDS: [3 ch][18 rows][136] (col 3 = left halo, 4..131 interior, 132 right halo).
// Histogram: per-thread register bins via tent weights -> shfl_xor 8-lane
// reduce -> 4-wave LDS combine. No atomics.
__global__ __launch_bounds__(256) void hog_hist_kernel(const float* __restrict__ im,
                                                       float* __restrict__ hist) {
    const int bid = blockIdx.x;             // ((b*32+cy)*4 + cxg)
    const int b   = bid >> 7;
    const int cy  = (bid >> 2) & 31;
    const int cxg = bid & 3;

    __shared__ __align__(16) float sT[NCH][18][136];
    __shared__ float swp[4][8][NBINS];      // [wave][local cell][bin]

    const int t = threadIdx.x;
    const int y0 = cy * 16 - 1;             // global row of LDS row 0
    const int x0 = cxg * 128;               // global col of LDS col 4
    const float* imb = im + (size_t)b * NCH * IMG_H * IMG_W;

    // ---- stage interior: 54 rows (3ch x 18) x 32 float4 ----
    {
        const int x4 = t & 31;
        const int rb = t >> 5;              // 0..7
#pragma unroll
        for (int k = 0; k < 7; ++k) {
            int rowid = rb + 8 * k;         // 0..55
            if (rowid < NCH * 18) {
                int c  = rowid / 18;
                int yy = rowid - c * 18;
                int gy = refl(y0 + yy, IMG_H);
                const float4 v = *(const float4*)(imb + ((size_t)c * IMG_H + gy) * IMG_W + x0 + 4 * x4);
                *(float4*)&sT[c][yy][4 + 4 * x4] = v;
            }
        }
        // halo columns: 3ch x 18 rows x 2 sides = 108 scalars
        if (t < 108) {
            int side = t & 1;
            int rid  = t >> 1;
            int c    = rid / 18;
            int yy   = rid - c * 18;
            int gy   = refl(y0 + yy, IMG_H);
            int gx   = refl(side ? x0 + 128 : x0 - 1, IMG_W);
            sT[c][yy][side ? 132 : 3] = imb[((size_t)c * IMG_H + gy) * IMG_W + gx];
        }
    }
    __syncthreads();

    // ---- compute: thread owns pixel cols (4+2cp, 5+2cp), rows pr..pr+3 ----
    const int cp = t & 63;                  // column pair 0..63
    const int rq = t >> 6;                  // wave id / row quad
    const int pr = rq * 4;                  // window rows pr..pr+5
    const int lxm1 = 3 + 2 * cp;            // left of 4-col window

    float bn[2][4], bgx[2][4], bgy[2][4];
#pragma unroll
    for (int e = 0; e < 2; ++e)
#pragma unroll
        for (int p = 0; p < 4; ++p) { bn[e][p] = -1.0f; bgx[e][p] = 0.0f; bgy[e][p] = 0.0f; }

#pragma unroll
    for (int c = 0; c < NCH; ++c) {
        float a[6][4];
#pragma unroll
        for (int j = 0; j < 6; ++j) {
            const float* rowp = &sT[c][pr + j][lxm1];
            a[j][0] = rowp[0]; a[j][1] = rowp[1]; a[j][2] = rowp[2]; a[j][3] = rowp[3];
        }
        // row diffs (exact original subtractions per pixel window)
        float rdE[6], rdO[6];
#pragma unroll
        for (int j = 0; j < 6; ++j) {
            rdE[j] = a[j][2] - a[j][0];
            rdO[j] = a[j][3] - a[j][1];
        }
        // column diffs cd[col][p] = a[p+2][col] - a[p][col]
        float cd[4][4];
#pragma unroll
        for (int p = 0; p < 4; ++p)
#pragma unroll
            for (int cc = 0; cc < 4; ++cc) cd[cc][p] = a[p + 2][cc] - a[p][cc];

#pragma unroll
        for (int p = 0; p < 4; ++p) {
            // identical association to the verified kernel:
            float gxE = (rdE[p] + 2.0f * rdE[p + 1]) + rdE[p + 2];
            float gyE = (cd[0][p] + 2.0f * cd[1][p]) + cd[2][p];
            float nE  = sqrtf(gxE * gxE + gyE * gyE);
            if (nE > bn[0][p]) { bn[0][p] = nE; bgx[0][p] = gxE; bgy[0][p] = gyE; }
            float gxO = (rdO[p] + 2.0f * rdO[p + 1]) + rdO[p + 2];
            float gyO = (cd[1][p] + 2.0f * cd[2][p]) + cd[3][p];
            float nO  = sqrtf(gxO * gxO + gyO * gyO);
            if (nO > bn[1][p]) { bn[1][p] = nO; bgx[1][p] = gxO; bgy[1][p] = gyO; }
        }
    }

    const float PI_F  = (float)M_PI;
    const float HPI_F = (float)(M_PI / 2.0);
    const float GAIN  = (float)(9.0 / M_PI);
    // minimax odd poly for atan on [0,1], max err ~2e-5 rad
    const float C1  = 0.99997726f, C3 = -0.33262347f, C5 = 0.19354346f;
    const float C7  = -0.11643287f, C9 = 0.05265332f, C11 = -0.01172120f;

    float acc[NBINS];
#pragma unroll
    for (int k = 0; k < NBINS; ++k) acc[k] = 0.0f;

#pragma unroll
    for (int e = 0; e < 2; ++e) {
#pragma unroll
        for (int p = 0; p < 4; ++p) {
            float gx = bgx[e][p], gy = bgy[e][p], n = bn[e][p];
            float ax = fabsf(gx), ay = fabsf(gy);
            float mn = fminf(ax, ay), mx = fmaxf(ax, ay);
            float r  = __fdividef(mn, mx + 1e-37f);
            float r2 = r * r;
            float at = r * (C1 + r2 * (C3 + r2 * (C5 + r2 * (C7 + r2 * (C9 + r2 * C11)))));
            if (ay > ax) at = HPI_F - at;
            if ((__float_as_uint(gx) ^ __float_as_uint(gy)) & 0x80000000u) at = PI_F - at;
            // at = atan2(gy,gx) mod pi, in [0, pi]
            float fp = GAIN * at;           // [0, 9]

            // tent binning: bin k gets n * max(0, 1-|fp-k|); bin 0 wraps at 9
            float w0 = fmaxf(1.0f - fabsf(fp), 0.0f) + fmaxf(1.0f - fabsf(fp - 9.0f), 0.0f);
            acc[0] = fmaf(w0, n, acc[0]);
#pragma unroll
            for (int k = 1; k < NBINS; ++k) {
                float wk = fmaxf(1.0f - fabsf(fp - (float)k), 0.0f);
                acc[k] = fmaf(wk, n, acc[k]);
            }
        }
    }

    // ---- reduce: 8-lane butterfly within each cell group ----
#pragma unroll
    for (int m = 1; m <= 4; m <<= 1) {
#pragma unroll
        for (int k = 0; k < NBINS; ++k)
            acc[k] += __shfl_xor(acc[k], m, 64);
    }

    if ((cp & 7) == 0) {
        const int cl = cp >> 3;             // local cell 0..7
#pragma unroll
        for (int k = 0; k < NBINS; ++k) swp[rq][cl][k] = acc[k];
    }
    __syncthreads();

    if (t < 8 * NBINS) {
        int cl  = t / NBINS;
        int bin = t - cl * NBINS;
        float sum = swp[0][cl][bin] + swp[1][cl][bin]
                  + swp[2][cl][bin] + swp[3][cl][bin];
        int cellX = cxg * 8 + cl;
        size_t cell = ((size_t)b * HC + cy) * WC + cellX;
        hist[cell * NBINS + bin] = sum * (1.0f / 256.0f);
    }
}

// One thread per output block: gather 2x2 cells x 9 bins, L2-Hys normalize.
__global__ __launch_bounds__(256) void hog_norm_kernel(const float* __restrict__ hist,
                                                       float* __restrict__ out) {
    int idx = blockIdx.x * 256 + threadIdx.x;  // b*961 + i*31 + j
    if (idx >= NB_ * HB * WB) return;
    int b = idx / (HB * WB);
    int r = idx - b * (HB * WB);
    int i = r / WB;
    int j = r - i * WB;

    float v[36];
    float ss = 0.0f;
#pragma unroll
    for (int bi = 0; bi < 2; ++bi) {
#pragma unroll
        for (int bj = 0; bj < 2; ++bj) {
            const float* hp = hist + (size_t)(((b * HC) + (i + bi)) * WC + (j + bj)) * NBINS;
#pragma unroll
            for (int k = 0; k < NBINS; ++k) {
                float x = hp[k];
                v[(bi * 2 + bj) * NBINS + k] = x;
                ss += x * x;
            }
        }
    }
    float inv1 = 1.0f / (sqrtf(ss) + 1e-10f);
    float ss2 = 0.0f;
#pragma unroll
    for (int k = 0; k < 36; ++k) {
        float tt = fminf(v[k] * inv1, 0.2f);
        v[k] = tt;
        ss2 += tt * tt;
    }
    float inv2 = 1.0f / (sqrtf(ss2) + 1e-10f);
    float* op = out + (size_t)idx * 36;
#pragma unroll
    for (int k = 0; k < 36; ++k) op[k] = v[k] * inv2;
}

extern "C" void kernel_launch(void* const* d_in, const int* in_sizes, int n_in,
                              void* d_out, int out_size, void* d_ws, size_t ws_size,
                              hipStream_t stream) {
    const float* im = (const float*)d_in[0];
    float* out = (float*)d_out;
    float* hist = (float*)d_ws;  // 16*32*32*9 floats = 589,824 bytes

    hog_hist_kernel<<<NB_ * HC * 4, 256, 0, stream>>>(im, hist);

    int nout_blocks = NB_ * HB * WB;           // 15376
    hog_norm_kernel<<<(nout_blocks + 255) / 256, 256, 0, stream>>>(hist, out);
}